// Round 6
// baseline (784.448 us; speedup 1.0000x reference)
//
#include <hip/hip_runtime.h>

typedef unsigned short u16;
typedef __attribute__((ext_vector_type(4))) float f32x4;
typedef __attribute__((ext_vector_type(8))) short bf16x8;
typedef __attribute__((ext_vector_type(4))) short bf16x4;
typedef __attribute__((ext_vector_type(2))) unsigned uint32x2;

#ifndef __has_builtin
#define __has_builtin(x) 0
#endif

__device__ __forceinline__ u16 f2bf(float f) {
  unsigned u = __builtin_bit_cast(unsigned, f);
  u += 0x7FFFu + ((u >> 16) & 1u);   // round-to-nearest-even
  return (u16)(u >> 16);
}

__device__ __forceinline__ void load16(const void* g, void* l) {
  __builtin_amdgcn_global_load_lds((const __attribute__((address_space(1))) void*)g,
                                   (__attribute__((address_space(3))) void*)l, 16, 0, 0);
}

__device__ __forceinline__ unsigned cvt_pk_bf16(float lo, float hi) {
  unsigned r;
  asm("v_cvt_pk_bf16_f32 %0, %1, %2" : "=v"(r) : "v"(lo), "v"(hi));
  return r;
}

// 16x16x16 bf16 MFMA (4 bf16/lane operands). Builtin if available, else asm
// with early-clobber dest (D must not alias A/B) + hazard nops.
__device__ __forceinline__ f32x4 mfma16_bf16(bf16x4 a, bf16x4 b, f32x4 c) {
#if __has_builtin(__builtin_amdgcn_mfma_f32_16x16x16bf16_1k)
  return __builtin_amdgcn_mfma_f32_16x16x16bf16_1k(a, b, c, 0, 0, 0);
#else
  f32x4 d;
  asm volatile("v_mfma_f32_16x16x16_bf16 %0, %1, %2, %3\n\ts_nop 7\n\ts_nop 3"
               : "=&v"(d) : "v"(a), "v"(b), "v"(c));
  return d;
#endif
}

#define FENCE() asm volatile("" ::: "memory")
#define BARRIER() do { FENCE(); __builtin_amdgcn_s_barrier(); FENCE(); } while (0)
#define WAIT_VM2() asm volatile("s_waitcnt vmcnt(2)" ::: "memory")
#define WAIT_VM0() asm volatile("s_waitcnt vmcnt(0)" ::: "memory")
#define LGKM0() asm volatile("s_waitcnt lgkmcnt(0)" ::: "memory")

// ---------------- converts ----------------

__global__ void cvt_x(const float* __restrict__ in, u16* __restrict__ out, int n4) {
  int i = blockIdx.x * 256 + threadIdx.x;
  if (i < n4) {
    float4 v = ((const float4*)in)[i];
    ushort4 o;
    o.x = f2bf(v.x); o.y = f2bf(v.y); o.z = f2bf(v.z); o.w = f2bf(v.w);
    ((ushort4*)out)[i] = o;
  }
}

// W[K][N] f32 -> Wt[N][K] bf16
__global__ void cvt_wt(const float* __restrict__ W, u16* __restrict__ Wt, int K, int N) {
  int idx = blockIdx.x * 256 + threadIdx.x;
  if (idx < N * K) {
    int n = idx / K, k = idx - n * K;
    Wt[idx] = f2bf(W[(size_t)k * N + n]);
  }
}

// ---- zero out-of-image K/V rows of qkvP (ref: padded tokens have k=0, v=0) ----
// rows: [b(8)][win(36)][mat'(2)->mat 1,2][h(12)][kidx(196)] ; 1,354,752 rows
__global__ void zero_pad(u16* __restrict__ qkvP) {
  int tid = blockIdx.x * 256 + threadIdx.x;
  if (tid >= 1354752) return;
  int kidx = tid % 196; int t2 = tid / 196;
  int h = t2 % 12;      int t3 = t2 / 12;
  int matp = t3 % 2;    int t4 = t3 / 2;
  int win = t4 % 36;    int b = t4 / 36;
  int wy = win / 6, wx = win - wy * 6;
  int iy = kidx / 14, ix = kidx - iy * 14;
  if (wy * 14 + iy < 80 && wx * 14 + ix < 80) return;   // valid pixel
  size_t base = ((size_t)((b * 36 + win) * 3 + (matp + 1)) * 12 + h) * 12544 + (size_t)kidx * 64;
  f32x4 z = {};
#pragma unroll
  for (int i = 0; i < 8; i++) ((f32x4*)(qkvP + base))[i] = z;
}

// ---------------- 256x256 8-phase GEMM core (BK=64, K=768, 12 K-tiles) -------
// (verified in round 1)

template <int MB, int NB>
__device__ __forceinline__ void mfma_quad(f32x4 (&acc)[8][4], const bf16x8 (&af)[4][2],
                                          const bf16x8 (&bf_)[4][2]) {
  __builtin_amdgcn_s_setprio(1);
#pragma unroll
  for (int mf = 0; mf < 4; mf++)
#pragma unroll
    for (int nf = 0; nf < 2; nf++) {
      acc[MB + mf][NB + nf] = __builtin_amdgcn_mfma_f32_16x16x32_bf16(
          af[mf][0], bf_[NB + nf][0], acc[MB + mf][NB + nf], 0, 0, 0);
      acc[MB + mf][NB + nf] = __builtin_amdgcn_mfma_f32_16x16x32_bf16(
          af[mf][1], bf_[NB + nf][1], acc[MB + mf][NB + nf], 0, 0, 0);
    }
  __builtin_amdgcn_s_setprio(0);
}

__device__ __forceinline__ void mm256_core(const u16* __restrict__ A,
                                           const u16* __restrict__ Bt,
                                           int bm, int bn,
                                           u16* lds, f32x4 (&acc)[8][4]) {
  const int K = 768;
  const int t = threadIdx.x;
  const int lane = t & 63, wave = t >> 6;
  const int wm = wave >> 2, wn = wave & 3;
  const int colq = lane & 15, quad = lane >> 4;

  const u16* Ab = A + (size_t)bm * 256 * K;
  const u16* Bb = Bt + (size_t)bn * 256 * K;

  u16* const lA = lds;             // [2][16384]
  u16* const lB = lds + 32768;     // [2][16384]

  const int srow = t >> 3;
  const int gslot = (t & 7) ^ (srow & 7);

#define STAGE_(gb, lb)                                                          \
  do {                                                                          \
    load16((gb) + (size_t)srow * K + gslot * 8, (lb) + t * 8);                  \
    load16((gb) + (size_t)(srow + 64) * K + gslot * 8, (lb) + (t + 512) * 8);   \
  } while (0)
#define STAGE_A(jj, h) STAGE_(Ab + (size_t)((h) * 128) * K + (jj) * 64, \
                              lA + ((jj) & 1) * 16384 + (h) * 8192)
#define STAGE_B(jj, h) STAGE_(Bb + (size_t)((h) * 128) * K + (jj) * 64, \
                              lB + ((jj) & 1) * 16384 + (h) * 8192)

  const int arow_lo = wm * 128 + colq;
  const int brow_lo = wn * 64 + colq;
  const int swz = (colq & 7) << 3;
#define RD(buf, row, kk) (*(const bf16x8*)&(buf)[(row) * 64 + (((kk) * 32 + quad * 8) ^ swz)])

  bf16x8 af[4][2], bf_[4][2];

  STAGE_A(0, 0); STAGE_A(0, 1); STAGE_B(0, 0); STAGE_B(0, 1);
  STAGE_A(1, 0);
  WAIT_VM2();
  BARRIER();

#pragma unroll 2
  for (int j = 0; j < 12; ++j) {
    const u16* cA = lA + (j & 1) * 16384;
    const u16* cB = lB + (j & 1) * 16384;

    // P1
#pragma unroll
    for (int mf = 0; mf < 4; mf++) {
      af[mf][0] = RD(cA, arow_lo + mf * 16, 0);
      af[mf][1] = RD(cA, arow_lo + mf * 16, 1);
    }
#pragma unroll
    for (int nf = 0; nf < 2; nf++) {
      bf_[nf][0] = RD(cB, brow_lo + nf * 16, 0);
      bf_[nf][1] = RD(cB, brow_lo + nf * 16, 1);
    }
    if (j < 11) STAGE_A(j + 1, 1);
    BARRIER();
    mfma_quad<0, 0>(acc, af, bf_);
    LGKM0();
    BARRIER();

    // P2
#pragma unroll
    for (int nf = 0; nf < 2; nf++) {
      bf_[2 + nf][0] = RD(cB, brow_lo + (2 + nf) * 16, 0);
      bf_[2 + nf][1] = RD(cB, brow_lo + (2 + nf) * 16, 1);
    }
    if (j < 11) STAGE_B(j + 1, 0);
    BARRIER();
    mfma_quad<0, 2>(acc, af, bf_);
    LGKM0();
    BARRIER();

    // P3
#pragma unroll
    for (int mf = 0; mf < 4; mf++) {
      af[mf][0] = RD(cA, arow_lo + 64 + mf * 16, 0);
      af[mf][1] = RD(cA, arow_lo + 64 + mf * 16, 1);
    }
    if (j < 11) STAGE_B(j + 1, 1);
    BARRIER();
    mfma_quad<4, 0>(acc, af, bf_);
    LGKM0();
    BARRIER();

    // P4
    if (j < 10) STAGE_A(j + 2, 0);
    BARRIER();
    mfma_quad<4, 2>(acc, af, bf_);
    if (j < 10) { WAIT_VM2(); }
    else if (j < 11) { WAIT_VM0(); }
    BARRIER();
  }
#undef RD
#undef STAGE_A
#undef STAGE_B
#undef STAGE_
}

// ---------------- GEMM1: x @ Wqkv, scatter epilogue into windowed layout ----

__global__ __launch_bounds__(512, 2) void gemm_qkv(const u16* __restrict__ A,
                                                   const u16* __restrict__ Bt,
                                                   u16* __restrict__ qkvP) {
  __shared__ __align__(16) u16 lds[65536];
  const int nx = gridDim.x;
  const int nwg = nx * gridDim.y;
  const int bid = blockIdx.y * nx + blockIdx.x;
  const int cpx = nwg >> 3;
  const int sid = (bid & 7) * cpx + (bid >> 3);
  const int bm = sid / nx, bn = sid - bm * nx;

  f32x4 acc[8][4] = {};
  mm256_core(A, Bt, bm, bn, lds, acc);

  const int t = threadIdx.x;
  const int lane = t & 63, wave = t >> 6;
  const int wm = wave >> 2, wn = wave & 3;
  const int colq = lane & 15, quad = lane >> 4;

  const int c64 = bn * 4 + wn;
  const int mat = c64 / 12;
  const int hh = c64 - mat * 12;
  const int r0 = bm * 256 + wm * 128 + quad * 4;
#pragma unroll
  for (int mf = 0; mf < 8; mf++) {
#pragma unroll
    for (int r = 0; r < 4; r++) {
      int row = r0 + mf * 16 + r;
      int bb = row / 6400;
      int rem = row - bb * 6400;
      int y = rem / 80, x = rem - (rem / 80) * 80;
      int wy = y / 14, wx = x / 14;
      int iy = y - wy * 14, ix = x - wx * 14;
      int win = wy * 6 + wx;
      int kidx = iy * 14 + ix;
      size_t base = ((size_t)((bb * 36 + win) * 3 + mat) * 12 + hh) * 12544 + (size_t)kidx * 64;
#pragma unroll
      for (int nf = 0; nf < 4; nf++)
        qkvP[base + nf * 16 + colq] = f2bf(acc[mf][nf][r]);
    }
  }
}

// ---------------- GEMM2: aout @ Wproj + bias -> f32 ----------------

__global__ __launch_bounds__(512, 2) void gemm_proj(const u16* __restrict__ A,
                                                    const u16* __restrict__ Bt,
                                                    float* __restrict__ C,
                                                    const float* __restrict__ bias) {
  __shared__ __align__(16) u16 lds[65536];
  const int nx = gridDim.x;
  const int nwg = nx * gridDim.y;
  const int bid = blockIdx.y * nx + blockIdx.x;
  const int cpx = nwg >> 3;
  const int sid = (bid & 7) * cpx + (bid >> 3);
  const int bm = sid / nx, bn = sid - bm * nx;

  f32x4 acc[8][4] = {};
  mm256_core(A, Bt, bm, bn, lds, acc);

  const int t = threadIdx.x;
  const int lane = t & 63, wave = t >> 6;
  const int wm = wave >> 2, wn = wave & 3;
  const int colq = lane & 15, quad = lane >> 4;

  const int r0 = bm * 256 + wm * 128 + quad * 4;
  const int c0 = bn * 256 + wn * 64 + colq;
  float bv[4];
#pragma unroll
  for (int nf = 0; nf < 4; nf++) bv[nf] = bias[c0 + nf * 16];
#pragma unroll
  for (int mf = 0; mf < 8; mf++)
#pragma unroll
    for (int nf = 0; nf < 4; nf++)
#pragma unroll
      for (int r = 0; r < 4; r++)
        C[(size_t)(r0 + mf * 16 + r) * 768 + (c0 + nf * 16)] = acc[mf][nf][r] + bv[nf];
}

// ---------------- windowed attention (v2s: r4-verified body + strip split) ---
// grid (12, 36, 16): z = b*2 + half; half 0 -> strips 0..6, half 1 -> 7..12.
// Body is BYTE-IDENTICAL to the round-4 passing version except mt init/bound.
// sK [208][64] u16, granule-XOR swizzle (g^(row&7)); staged via global_load_lds
//   with pre-swizzled source.
// sVt: per-nt-block perm layout: byte(nt,d,q) = nt*2048 + (d>>4)*512 + q*128
//   + ((d&15)^(q<<2))*8 ; filled by v_perm reg-transpose; conflict-free b64.
// QK swapped: s[nt] = mfma(K,Q) -> lane holds P[query=colq][key=nt*16+quad*4+r]
//   = exactly the 16x16x16 MFMA A-fragment -> PV needs NO data movement.
// Out-of-image K/V rows pre-zeroed by zero_pad (logit 0 / zero V contribution).

__global__ __launch_bounds__(256, 3) void win_attn(const u16* __restrict__ qkvP,
                                                   u16* __restrict__ out) {
  __shared__ __align__(16) u16 sK[208 * 64];     // 26624 B
  __shared__ __align__(16) u16 sVt[13 * 1024];   // 26624 B

  const int h = blockIdx.x, win = blockIdx.y, bz = blockIdx.z;
  const int b = bz >> 1, half = bz & 1;
  const int wy = win / 6, wx = win - wy * 6;
  const int y0 = wy * 14, x0 = wx * 14;
  const int t = threadIdx.x, wave = t >> 6, lane = t & 63;
  const int colq = lane & 15, quad = lane >> 4;

  const size_t bwin = (size_t)(b * 36 + win) * 3;
  const u16* qbase = qkvP + ((bwin + 0) * 12 + h) * 12544;
  const u16* kbase = qkvP + ((bwin + 1) * 12 + h) * 12544;
  const u16* vbase = qkvP + ((bwin + 2) * 12 + h) * 12544;

  // ---- K stage: LDS granule g of row holds global granule g^(row&7) ----
  for (int s = t; s < 1664; s += 256) {
    int row = s >> 3, g = s & 7;
    int srow = row < 196 ? row : 0;          // rows 196..207: dup row 0, masked later
    load16(kbase + srow * 64 + ((g ^ (row & 7)) << 3), (u16*)sK + s * 8);
  }

  // ---- V reg-transpose into perm layout; keys >=196 zeroed ----
  for (int u = t; u < 416; u += 256) {
    int kq = u >> 3, dg = u & 7;             // key-quad 0..51, d-octet 0..7
    int nt = kq >> 2, q = kq & 3;
    uint4 a0 = {}, a1 = {}, a2 = {}, a3 = {};
    if (kq < 49) {
      const uint4* vp = (const uint4*)(vbase + kq * 256 + dg * 8);
      a0 = vp[0]; a1 = vp[8]; a2 = vp[16]; a3 = vp[24];
    }
    const unsigned* r0p = (const unsigned*)&a0;
    const unsigned* r1p = (const unsigned*)&a1;
    const unsigned* r2p = (const unsigned*)&a2;
    const unsigned* r3p = (const unsigned*)&a3;
#pragma unroll
    for (int dd = 0; dd < 8; dd++) {
      unsigned sel = (dd & 1) ? 0x07060302u : 0x05040100u;
      unsigned lo = __builtin_amdgcn_perm(r1p[dd >> 1], r0p[dd >> 1], sel);  // k0,k1
      unsigned hi = __builtin_amdgcn_perm(r3p[dd >> 1], r2p[dd >> 1], sel);  // k2,k3
      int byteoff = nt * 2048 + (dg >> 1) * 512 + q * 128 +
                    ((((dg & 1) * 8 + dd) ^ (q << 2)) << 3);
      uint32x2 wv; wv[0] = lo; wv[1] = hi;
      *(uint32x2*)((char*)sVt + byteoff) = wv;
    }
  }
  __syncthreads();   // drains vmcnt (global_load_lds) + lgkm (ds_writes)

  const int kswz = (colq & 7) << 3;
  const int vtoff = quad * 128 + ((colq ^ (quad << 2)) << 3);

  // ---- per-wave 16-query strips (this block's half only) ----
  const int mtEnd = half ? 13 : 7;
  int mt = (half ? 7 : 0) + wave;
  const u16* qp = qbase + (mt * 16 + colq) * 64 + quad * 8;
  bf16x8 qa0 = *(const bf16x8*)qp;
  bf16x8 qa1 = *(const bf16x8*)(qp + 32);
  while (mt < mtEnd) {
    int mtn = mt + 4;
    bf16x8 qn0 = qa0, qn1 = qa1;
    if (mtn < mtEnd) {   // prefetch next strip's Q
      const u16* qp2 = qbase + (mtn * 16 + colq) * 64 + quad * 8;
      qn0 = *(const bf16x8*)qp2;
      qn1 = *(const bf16x8*)(qp2 + 32);
    }

    // ---- swapped QK^T: s[nt][r] = S[key=nt*16+quad*4+r][query=colq] ----
    f32x4 s[13];
    __builtin_amdgcn_s_setprio(1);
#pragma unroll
    for (int nt = 0; nt < 13; nt++) {
      const u16* kr = &sK[(nt * 16 + colq) * 64];
      bf16x8 kb0 = *(const bf16x8*)&kr[(quad * 8) ^ kswz];
      bf16x8 kb1 = *(const bf16x8*)&kr[(32 + quad * 8) ^ kswz];
      f32x4 a = {0.f, 0.f, 0.f, 0.f};
      a = __builtin_amdgcn_mfma_f32_16x16x32_bf16(kb0, qa0, a, 0, 0, 0);
      a = __builtin_amdgcn_mfma_f32_16x16x32_bf16(kb1, qa1, a, 0, 0, 0);
      s[nt] = a;
    }
    __builtin_amdgcn_s_setprio(0);

    // ---- in-register softmax over keys (per-lane query = colq) ----
    float mx = -1e30f;
#pragma unroll
    for (int nt = 0; nt < 13; nt++)
#pragma unroll
      for (int r = 0; r < 4; r++) {
        float v = s[nt][r] * 0.125f;
        if (nt == 12 && quad != 0) v = -1e30f;   // keys >= 196 don't exist
        s[nt][r] = v;
        mx = fmaxf(mx, v);
      }
    mx = fmaxf(mx, __shfl_xor(mx, 16));
    mx = fmaxf(mx, __shfl_xor(mx, 32));
    float sm = 0.f;
#pragma unroll
    for (int nt = 0; nt < 13; nt++)
#pragma unroll
      for (int r = 0; r < 4; r++) {
        float e = __expf(s[nt][r] - mx);
        s[nt][r] = e;
        sm += e;
      }
    sm += __shfl_xor(sm, 16);
    sm += __shfl_xor(sm, 32);
    float rs = 1.0f / sm;

    // ---- normalize + pack to bf16 (A-fragment layout, no movement) ----
    unsigned pk0[13], pk1[13];
#pragma unroll
    for (int nt = 0; nt < 13; nt++) {
      pk0[nt] = cvt_pk_bf16(s[nt][0] * rs, s[nt][1] * rs);
      pk1[nt] = cvt_pk_bf16(s[nt][2] * rs, s[nt][3] * rs);
    }

    // ---- O = P V via 16x16x16 MFMAs, conflict-free b64 V reads ----
    f32x4 o[4] = {};
    __builtin_amdgcn_s_setprio(1);
#pragma unroll
    for (int nt = 0; nt < 13; nt++) {
      uint32x2 pw; pw[0] = pk0[nt]; pw[1] = pk1[nt];
      bf16x4 pa = __builtin_bit_cast(bf16x4, pw);
      const char* vtb = (const char*)sVt + nt * 2048 + vtoff;
#pragma unroll
      for (int dt = 0; dt < 4; dt++) {
        bf16x4 vb = *(const bf16x4*)(vtb + dt * 512);
        o[dt] = mfma16_bf16(pa, vb, o[dt]);
      }
    }
    __builtin_amdgcn_s_setprio(0);

    // ---- write valid rows: o[dt][r] = O[query=quad*4+r][d=dt*16+colq] ----
#pragma unroll
    for (int r = 0; r < 4; r++) {
      int qr = mt * 16 + quad * 4 + r;
      if (qr < 196) {
        int iy = qr / 14, ix = qr - (qr / 14) * 14;
        int y = y0 + iy, x = x0 + ix;
        if (y < 80 && x < 80) {
          size_t off = ((size_t)(b * 6400 + y * 80 + x)) * 768 + h * 64 + colq;
#pragma unroll
          for (int dt = 0; dt < 4; dt++) out[off + dt * 16] = f2bf(o[dt][r]);
        }
      }
    }
    qa0 = qn0; qa1 = qn1;
    mt = mtn;
  }
}

// ---------------- launch ----------------

extern "C" void kernel_launch(void* const* d_in, const int* in_sizes, int n_in,
                              void* d_out, int out_size, void* d_ws, size_t ws_size,
                              hipStream_t stream) {
  const float* x     = (const float*)d_in[0];
  const float* Wqkv  = (const float*)d_in[1];
  const float* Wproj = (const float*)d_in[2];
  const float* bproj = (const float*)d_in[3];

  char* ws = (char*)d_ws;
  const size_t QKVP_BYTES = (size_t)130056192 * 2 + 4096;
  const size_t X_BYTES    = (size_t)51200 * 768 * 2;
  const size_t WQT_BYTES  = (size_t)2304 * 768 * 2;
  u16* qkvP   = (u16*)ws;
  u16* xbf    = (u16*)(ws + QKVP_BYTES);
  u16* wqkvT  = (u16*)(ws + QKVP_BYTES + X_BYTES);
  u16* wprojT = (u16*)(ws + QKVP_BYTES + X_BYTES + WQT_BYTES);
  u16* aout   = xbf;  // x dead after GEMM1; attention fully overwrites before GEMM2

  cvt_x<<<38400, 256, 0, stream>>>(x, xbf, 9830400);
  cvt_wt<<<6912, 256, 0, stream>>>(Wqkv, wqkvT, 768, 2304);
  cvt_wt<<<2304, 256, 0, stream>>>(Wproj, wprojT, 768, 768);
  zero_pad<<<5292, 256, 0, stream>>>(qkvP);
  gemm_qkv<<<dim3(9, 200), 512, 0, stream>>>(xbf, wqkvT, qkvP);
  win_attn<<<dim3(12, 36, 16), 256, 0, stream>>>(qkvP, aout);
  gemm_proj<<<dim3(3, 200), 512, 0, stream>>>(aout, wprojT, (float*)d_out, bproj);
}

// Round 7
// 742.377 us; speedup vs baseline: 1.0567x; 1.0567x over previous
//
#include <hip/hip_runtime.h>

typedef unsigned short u16;
typedef __attribute__((ext_vector_type(4))) float f32x4;
typedef __attribute__((ext_vector_type(8))) short bf16x8;
typedef __attribute__((ext_vector_type(4))) short bf16x4;
typedef __attribute__((ext_vector_type(2))) unsigned uint32x2;

#ifndef __has_builtin
#define __has_builtin(x) 0
#endif

__device__ __forceinline__ u16 f2bf(float f) {
  unsigned u = __builtin_bit_cast(unsigned, f);
  u += 0x7FFFu + ((u >> 16) & 1u);   // round-to-nearest-even
  return (u16)(u >> 16);
}

__device__ __forceinline__ void load16(const void* g, void* l) {
  __builtin_amdgcn_global_load_lds((const __attribute__((address_space(1))) void*)g,
                                   (__attribute__((address_space(3))) void*)l, 16, 0, 0);
}

__device__ __forceinline__ unsigned cvt_pk_bf16(float lo, float hi) {
  unsigned r;
  asm("v_cvt_pk_bf16_f32 %0, %1, %2" : "=v"(r) : "v"(lo), "v"(hi));
  return r;
}

// 16x16x16 bf16 MFMA (4 bf16/lane operands). Builtin if available, else asm
// with early-clobber dest (D must not alias A/B) + hazard nops.
__device__ __forceinline__ f32x4 mfma16_bf16(bf16x4 a, bf16x4 b, f32x4 c) {
#if __has_builtin(__builtin_amdgcn_mfma_f32_16x16x16bf16_1k)
  return __builtin_amdgcn_mfma_f32_16x16x16bf16_1k(a, b, c, 0, 0, 0);
#else
  f32x4 d;
  asm volatile("v_mfma_f32_16x16x16_bf16 %0, %1, %2, %3\n\ts_nop 7\n\ts_nop 3"
               : "=&v"(d) : "v"(a), "v"(b), "v"(c));
  return d;
#endif
}

#define FENCE() asm volatile("" ::: "memory")
#define BARRIER() do { FENCE(); __builtin_amdgcn_s_barrier(); FENCE(); } while (0)
#define WAIT_VM2() asm volatile("s_waitcnt vmcnt(2)" ::: "memory")
#define WAIT_VM0() asm volatile("s_waitcnt vmcnt(0)" ::: "memory")
#define LGKM0() asm volatile("s_waitcnt lgkmcnt(0)" ::: "memory")

// ---------------- converts ----------------

__global__ void cvt_x(const float* __restrict__ in, u16* __restrict__ out, int n4) {
  int i = blockIdx.x * 256 + threadIdx.x;
  if (i < n4) {
    float4 v = ((const float4*)in)[i];
    ushort4 o;
    o.x = f2bf(v.x); o.y = f2bf(v.y); o.z = f2bf(v.z); o.w = f2bf(v.w);
    ((ushort4*)out)[i] = o;
  }
}

// W[K][N] f32 -> Wt[N][K] bf16
__global__ void cvt_wt(const float* __restrict__ W, u16* __restrict__ Wt, int K, int N) {
  int idx = blockIdx.x * 256 + threadIdx.x;
  if (idx < N * K) {
    int n = idx / K, k = idx - n * K;
    Wt[idx] = f2bf(W[(size_t)k * N + n]);
  }
}

// ---- zero out-of-image K/V rows of qkvP (ref: padded tokens have k=0, v=0) ----
// rows: [b(8)][win(36)][mat'(2)->mat 1,2][h(12)][kidx(196)] ; 1,354,752 rows
__global__ void zero_pad(u16* __restrict__ qkvP) {
  int tid = blockIdx.x * 256 + threadIdx.x;
  if (tid >= 1354752) return;
  int kidx = tid % 196; int t2 = tid / 196;
  int h = t2 % 12;      int t3 = t2 / 12;
  int matp = t3 % 2;    int t4 = t3 / 2;
  int win = t4 % 36;    int b = t4 / 36;
  int wy = win / 6, wx = win - wy * 6;
  int iy = kidx / 14, ix = kidx - iy * 14;
  if (wy * 14 + iy < 80 && wx * 14 + ix < 80) return;   // valid pixel
  size_t base = ((size_t)((b * 36 + win) * 3 + (matp + 1)) * 12 + h) * 12544 + (size_t)kidx * 64;
  f32x4 z = {};
#pragma unroll
  for (int i = 0; i < 8; i++) ((f32x4*)(qkvP + base))[i] = z;
}

// ---------------- 256x256 8-phase GEMM core (BK=64, K=768, 12 K-tiles) -------
// (verified in round 1)

template <int MB, int NB>
__device__ __forceinline__ void mfma_quad(f32x4 (&acc)[8][4], const bf16x8 (&af)[4][2],
                                          const bf16x8 (&bf_)[4][2]) {
  __builtin_amdgcn_s_setprio(1);
#pragma unroll
  for (int mf = 0; mf < 4; mf++)
#pragma unroll
    for (int nf = 0; nf < 2; nf++) {
      acc[MB + mf][NB + nf] = __builtin_amdgcn_mfma_f32_16x16x32_bf16(
          af[mf][0], bf_[NB + nf][0], acc[MB + mf][NB + nf], 0, 0, 0);
      acc[MB + mf][NB + nf] = __builtin_amdgcn_mfma_f32_16x16x32_bf16(
          af[mf][1], bf_[NB + nf][1], acc[MB + mf][NB + nf], 0, 0, 0);
    }
  __builtin_amdgcn_s_setprio(0);
}

__device__ __forceinline__ void mm256_core(const u16* __restrict__ A,
                                           const u16* __restrict__ Bt,
                                           int bm, int bn,
                                           u16* lds, f32x4 (&acc)[8][4]) {
  const int K = 768;
  const int t = threadIdx.x;
  const int lane = t & 63, wave = t >> 6;
  const int wm = wave >> 2, wn = wave & 3;
  const int colq = lane & 15, quad = lane >> 4;

  const u16* Ab = A + (size_t)bm * 256 * K;
  const u16* Bb = Bt + (size_t)bn * 256 * K;

  u16* const lA = lds;             // [2][16384]
  u16* const lB = lds + 32768;     // [2][16384]

  const int srow = t >> 3;
  const int gslot = (t & 7) ^ (srow & 7);

#define STAGE_(gb, lb)                                                          \
  do {                                                                          \
    load16((gb) + (size_t)srow * K + gslot * 8, (lb) + t * 8);                  \
    load16((gb) + (size_t)(srow + 64) * K + gslot * 8, (lb) + (t + 512) * 8);   \
  } while (0)
#define STAGE_A(jj, h) STAGE_(Ab + (size_t)((h) * 128) * K + (jj) * 64, \
                              lA + ((jj) & 1) * 16384 + (h) * 8192)
#define STAGE_B(jj, h) STAGE_(Bb + (size_t)((h) * 128) * K + (jj) * 64, \
                              lB + ((jj) & 1) * 16384 + (h) * 8192)

  const int arow_lo = wm * 128 + colq;
  const int brow_lo = wn * 64 + colq;
  const int swz = (colq & 7) << 3;
#define RD(buf, row, kk) (*(const bf16x8*)&(buf)[(row) * 64 + (((kk) * 32 + quad * 8) ^ swz)])

  bf16x8 af[4][2], bf_[4][2];

  STAGE_A(0, 0); STAGE_A(0, 1); STAGE_B(0, 0); STAGE_B(0, 1);
  STAGE_A(1, 0);
  WAIT_VM2();
  BARRIER();

#pragma unroll 2
  for (int j = 0; j < 12; ++j) {
    const u16* cA = lA + (j & 1) * 16384;
    const u16* cB = lB + (j & 1) * 16384;

    // P1
#pragma unroll
    for (int mf = 0; mf < 4; mf++) {
      af[mf][0] = RD(cA, arow_lo + mf * 16, 0);
      af[mf][1] = RD(cA, arow_lo + mf * 16, 1);
    }
#pragma unroll
    for (int nf = 0; nf < 2; nf++) {
      bf_[nf][0] = RD(cB, brow_lo + nf * 16, 0);
      bf_[nf][1] = RD(cB, brow_lo + nf * 16, 1);
    }
    if (j < 11) STAGE_A(j + 1, 1);
    BARRIER();
    mfma_quad<0, 0>(acc, af, bf_);
    LGKM0();
    BARRIER();

    // P2
#pragma unroll
    for (int nf = 0; nf < 2; nf++) {
      bf_[2 + nf][0] = RD(cB, brow_lo + (2 + nf) * 16, 0);
      bf_[2 + nf][1] = RD(cB, brow_lo + (2 + nf) * 16, 1);
    }
    if (j < 11) STAGE_B(j + 1, 0);
    BARRIER();
    mfma_quad<0, 2>(acc, af, bf_);
    LGKM0();
    BARRIER();

    // P3
#pragma unroll
    for (int mf = 0; mf < 4; mf++) {
      af[mf][0] = RD(cA, arow_lo + 64 + mf * 16, 0);
      af[mf][1] = RD(cA, arow_lo + 64 + mf * 16, 1);
    }
    if (j < 11) STAGE_B(j + 1, 1);
    BARRIER();
    mfma_quad<4, 0>(acc, af, bf_);
    LGKM0();
    BARRIER();

    // P4
    if (j < 10) STAGE_A(j + 2, 0);
    BARRIER();
    mfma_quad<4, 2>(acc, af, bf_);
    if (j < 10) { WAIT_VM2(); }
    else if (j < 11) { WAIT_VM0(); }
    BARRIER();
  }
#undef RD
#undef STAGE_A
#undef STAGE_B
#undef STAGE_
}

// ---------------- GEMM1: x @ Wqkv, scatter epilogue into windowed layout ----
// Q (mat==0) is pre-scaled by 0.125 (= 2^-3, exact in bf16) so win_attn's
// logits need no scale: (Q*2^-3)·K == 2^-3*(Q·K) bit-for-bit.

__global__ __launch_bounds__(512, 2) void gemm_qkv(const u16* __restrict__ A,
                                                   const u16* __restrict__ Bt,
                                                   u16* __restrict__ qkvP) {
  __shared__ __align__(16) u16 lds[65536];
  const int nx = gridDim.x;
  const int nwg = nx * gridDim.y;
  const int bid = blockIdx.y * nx + blockIdx.x;
  const int cpx = nwg >> 3;
  const int sid = (bid & 7) * cpx + (bid >> 3);
  const int bm = sid / nx, bn = sid - bm * nx;

  f32x4 acc[8][4] = {};
  mm256_core(A, Bt, bm, bn, lds, acc);

  const int t = threadIdx.x;
  const int lane = t & 63, wave = t >> 6;
  const int wm = wave >> 2, wn = wave & 3;
  const int colq = lane & 15, quad = lane >> 4;

  const int c64 = bn * 4 + wn;
  const int mat = c64 / 12;
  const int hh = c64 - mat * 12;
  const float qscale = (mat == 0) ? 0.125f : 1.0f;
  const int r0 = bm * 256 + wm * 128 + quad * 4;
#pragma unroll
  for (int mf = 0; mf < 8; mf++) {
#pragma unroll
    for (int r = 0; r < 4; r++) {
      int row = r0 + mf * 16 + r;
      int bb = row / 6400;
      int rem = row - bb * 6400;
      int y = rem / 80, x = rem - (rem / 80) * 80;
      int wy = y / 14, wx = x / 14;
      int iy = y - wy * 14, ix = x - wx * 14;
      int win = wy * 6 + wx;
      int kidx = iy * 14 + ix;
      size_t base = ((size_t)((bb * 36 + win) * 3 + mat) * 12 + hh) * 12544 + (size_t)kidx * 64;
#pragma unroll
      for (int nf = 0; nf < 4; nf++)
        qkvP[base + nf * 16 + colq] = f2bf(acc[mf][nf][r] * qscale);
    }
  }
}

// ---------------- GEMM2: aout @ Wproj + bias -> f32 ----------------

__global__ __launch_bounds__(512, 2) void gemm_proj(const u16* __restrict__ A,
                                                    const u16* __restrict__ Bt,
                                                    float* __restrict__ C,
                                                    const float* __restrict__ bias) {
  __shared__ __align__(16) u16 lds[65536];
  const int nx = gridDim.x;
  const int nwg = nx * gridDim.y;
  const int bid = blockIdx.y * nx + blockIdx.x;
  const int cpx = nwg >> 3;
  const int sid = (bid & 7) * cpx + (bid >> 3);
  const int bm = sid / nx, bn = sid - bm * nx;

  f32x4 acc[8][4] = {};
  mm256_core(A, Bt, bm, bn, lds, acc);

  const int t = threadIdx.x;
  const int lane = t & 63, wave = t >> 6;
  const int wm = wave >> 2, wn = wave & 3;
  const int colq = lane & 15, quad = lane >> 4;

  const int r0 = bm * 256 + wm * 128 + quad * 4;
  const int c0 = bn * 256 + wn * 64 + colq;
  float bv[4];
#pragma unroll
  for (int nf = 0; nf < 4; nf++) bv[nf] = bias[c0 + nf * 16];
#pragma unroll
  for (int mf = 0; mf < 8; mf++)
#pragma unroll
    for (int nf = 0; nf < 4; nf++)
#pragma unroll
      for (int r = 0; r < 4; r++)
        C[(size_t)(r0 + mf * 16 + r) * 768 + (c0 + nf * 16)] = acc[mf][nf][r] + bv[nf];
}

// ---------------- windowed attention (v4: r4 body + tree softmax) ------------
// grid (12, 36, 8), block 256 (4 waves). LDS 53248 B.
// Identical to the round-4 verified kernel except:
//  (1) softmax max/sum use 4 parallel 13-deep chains + 2-level combine
//      (numerically identical: same max, same addends regrouped);
//  (2) no *0.125 on logits (Q pre-scaled in gemm_qkv, bit-exact).
// sK [208][64] u16, granule-XOR swizzle (g^(row&7)); staged via global_load_lds.
// sVt per-nt perm layout, filled by v_perm reg-transpose; conflict-free b64.
// QK swapped: s[nt] = mfma(K,Q) -> lane holds P[query=colq][key=nt*16+quad*4+r]
//   = exactly the 16x16x16 MFMA A-fragment -> PV needs NO data movement.
// Out-of-image K/V rows pre-zeroed by zero_pad (logit 0 / zero V contribution).

__global__ __launch_bounds__(256, 3) void win_attn(const u16* __restrict__ qkvP,
                                                   u16* __restrict__ out) {
  __shared__ __align__(16) u16 sK[208 * 64];     // 26624 B
  __shared__ __align__(16) u16 sVt[13 * 1024];   // 26624 B

  const int h = blockIdx.x, win = blockIdx.y, b = blockIdx.z;
  const int wy = win / 6, wx = win - wy * 6;
  const int y0 = wy * 14, x0 = wx * 14;
  const int t = threadIdx.x, wave = t >> 6, lane = t & 63;
  const int colq = lane & 15, quad = lane >> 4;

  const size_t bwin = (size_t)(b * 36 + win) * 3;
  const u16* qbase = qkvP + ((bwin + 0) * 12 + h) * 12544;
  const u16* kbase = qkvP + ((bwin + 1) * 12 + h) * 12544;
  const u16* vbase = qkvP + ((bwin + 2) * 12 + h) * 12544;

  // ---- K stage: LDS granule g of row holds global granule g^(row&7) ----
  for (int s = t; s < 1664; s += 256) {
    int row = s >> 3, g = s & 7;
    int srow = row < 196 ? row : 0;          // rows 196..207: dup row 0, masked later
    load16(kbase + srow * 64 + ((g ^ (row & 7)) << 3), (u16*)sK + s * 8);
  }

  // ---- V reg-transpose into perm layout; keys >=196 zeroed ----
  for (int u = t; u < 416; u += 256) {
    int kq = u >> 3, dg = u & 7;             // key-quad 0..51, d-octet 0..7
    int nt = kq >> 2, q = kq & 3;
    uint4 a0 = {}, a1 = {}, a2 = {}, a3 = {};
    if (kq < 49) {
      const uint4* vp = (const uint4*)(vbase + kq * 256 + dg * 8);
      a0 = vp[0]; a1 = vp[8]; a2 = vp[16]; a3 = vp[24];
    }
    const unsigned* r0p = (const unsigned*)&a0;
    const unsigned* r1p = (const unsigned*)&a1;
    const unsigned* r2p = (const unsigned*)&a2;
    const unsigned* r3p = (const unsigned*)&a3;
#pragma unroll
    for (int dd = 0; dd < 8; dd++) {
      unsigned sel = (dd & 1) ? 0x07060302u : 0x05040100u;
      unsigned lo = __builtin_amdgcn_perm(r1p[dd >> 1], r0p[dd >> 1], sel);  // k0,k1
      unsigned hi = __builtin_amdgcn_perm(r3p[dd >> 1], r2p[dd >> 1], sel);  // k2,k3
      int byteoff = nt * 2048 + (dg >> 1) * 512 + q * 128 +
                    ((((dg & 1) * 8 + dd) ^ (q << 2)) << 3);
      uint32x2 wv; wv[0] = lo; wv[1] = hi;
      *(uint32x2*)((char*)sVt + byteoff) = wv;
    }
  }
  __syncthreads();   // drains vmcnt (global_load_lds) + lgkm (ds_writes)

  const int kswz = (colq & 7) << 3;
  const int vtoff = quad * 128 + ((colq ^ (quad << 2)) << 3);

  // ---- per-wave 16-query strips ----
  int mt = wave;
  const u16* qp = qbase + (mt * 16 + colq) * 64 + quad * 8;
  bf16x8 qa0 = *(const bf16x8*)qp;
  bf16x8 qa1 = *(const bf16x8*)(qp + 32);
  while (mt < 13) {
    int mtn = mt + 4;
    bf16x8 qn0 = qa0, qn1 = qa1;
    if (mtn < 13) {   // prefetch next strip's Q
      const u16* qp2 = qbase + (mtn * 16 + colq) * 64 + quad * 8;
      qn0 = *(const bf16x8*)qp2;
      qn1 = *(const bf16x8*)(qp2 + 32);
    }

    // ---- swapped QK^T: s[nt][r] = S[key=nt*16+quad*4+r][query=colq] ----
    f32x4 s[13];
    __builtin_amdgcn_s_setprio(1);
#pragma unroll
    for (int nt = 0; nt < 13; nt++) {
      const u16* kr = &sK[(nt * 16 + colq) * 64];
      bf16x8 kb0 = *(const bf16x8*)&kr[(quad * 8) ^ kswz];
      bf16x8 kb1 = *(const bf16x8*)&kr[(32 + quad * 8) ^ kswz];
      f32x4 a = {0.f, 0.f, 0.f, 0.f};
      a = __builtin_amdgcn_mfma_f32_16x16x32_bf16(kb0, qa0, a, 0, 0, 0);
      a = __builtin_amdgcn_mfma_f32_16x16x32_bf16(kb1, qa1, a, 0, 0, 0);
      s[nt] = a;
    }
    __builtin_amdgcn_s_setprio(0);

    // ---- in-register softmax over keys (per-lane query = colq) ----
    // 4 parallel 13-deep chains + 2-level combine (same max/sum, regrouped).
    float mxr[4] = {-1e30f, -1e30f, -1e30f, -1e30f};
#pragma unroll
    for (int nt = 0; nt < 13; nt++)
#pragma unroll
      for (int r = 0; r < 4; r++) {
        float v = s[nt][r];
        if (nt == 12 && quad != 0) v = -1e30f;   // keys >= 196 don't exist
        s[nt][r] = v;
        mxr[r] = fmaxf(mxr[r], v);
      }
    float mx = fmaxf(fmaxf(mxr[0], mxr[1]), fmaxf(mxr[2], mxr[3]));
    mx = fmaxf(mx, __shfl_xor(mx, 16));
    mx = fmaxf(mx, __shfl_xor(mx, 32));
    float smr[4] = {0.f, 0.f, 0.f, 0.f};
#pragma unroll
    for (int nt = 0; nt < 13; nt++)
#pragma unroll
      for (int r = 0; r < 4; r++) {
        float e = __expf(s[nt][r] - mx);
        s[nt][r] = e;
        smr[r] += e;
      }
    float sm = (smr[0] + smr[1]) + (smr[2] + smr[3]);
    sm += __shfl_xor(sm, 16);
    sm += __shfl_xor(sm, 32);
    float rs = 1.0f / sm;

    // ---- normalize + pack to bf16 (A-fragment layout, no movement) ----
    unsigned pk0[13], pk1[13];
#pragma unroll
    for (int nt = 0; nt < 13; nt++) {
      pk0[nt] = cvt_pk_bf16(s[nt][0] * rs, s[nt][1] * rs);
      pk1[nt] = cvt_pk_bf16(s[nt][2] * rs, s[nt][3] * rs);
    }

    // ---- O = P V via 16x16x16 MFMAs, conflict-free b64 V reads ----
    f32x4 o[4] = {};
    __builtin_amdgcn_s_setprio(1);
#pragma unroll
    for (int nt = 0; nt < 13; nt++) {
      uint32x2 pw; pw[0] = pk0[nt]; pw[1] = pk1[nt];
      bf16x4 pa = __builtin_bit_cast(bf16x4, pw);
      const char* vtb = (const char*)sVt + nt * 2048 + vtoff;
#pragma unroll
      for (int dt = 0; dt < 4; dt++) {
        bf16x4 vb = *(const bf16x4*)(vtb + dt * 512);
        o[dt] = mfma16_bf16(pa, vb, o[dt]);
      }
    }
    __builtin_amdgcn_s_setprio(0);

    // ---- write valid rows: o[dt][r] = O[query=quad*4+r][d=dt*16+colq] ----
#pragma unroll
    for (int r = 0; r < 4; r++) {
      int qr = mt * 16 + quad * 4 + r;
      if (qr < 196) {
        int iy = qr / 14, ix = qr - (qr / 14) * 14;
        int y = y0 + iy, x = x0 + ix;
        if (y < 80 && x < 80) {
          size_t off = ((size_t)(b * 6400 + y * 80 + x)) * 768 + h * 64 + colq;
#pragma unroll
          for (int dt = 0; dt < 4; dt++) out[off + dt * 16] = f2bf(o[dt][r]);
        }
      }
    }
    qa0 = qn0; qa1 = qn1;
    mt = mtn;
  }
}

// ---------------- launch ----------------

extern "C" void kernel_launch(void* const* d_in, const int* in_sizes, int n_in,
                              void* d_out, int out_size, void* d_ws, size_t ws_size,
                              hipStream_t stream) {
  const float* x     = (const float*)d_in[0];
  const float* Wqkv  = (const float*)d_in[1];
  const float* Wproj = (const float*)d_in[2];
  const float* bproj = (const float*)d_in[3];

  char* ws = (char*)d_ws;
  const size_t QKVP_BYTES = (size_t)130056192 * 2 + 4096;
  const size_t X_BYTES    = (size_t)51200 * 768 * 2;
  const size_t WQT_BYTES  = (size_t)2304 * 768 * 2;
  u16* qkvP   = (u16*)ws;
  u16* xbf    = (u16*)(ws + QKVP_BYTES);
  u16* wqkvT  = (u16*)(ws + QKVP_BYTES + X_BYTES);
  u16* wprojT = (u16*)(ws + QKVP_BYTES + X_BYTES + WQT_BYTES);
  u16* aout   = xbf;  // x dead after GEMM1; attention fully overwrites before GEMM2

  cvt_x<<<38400, 256, 0, stream>>>(x, xbf, 9830400);
  cvt_wt<<<6912, 256, 0, stream>>>(Wqkv, wqkvT, 768, 2304);
  cvt_wt<<<2304, 256, 0, stream>>>(Wproj, wprojT, 768, 768);
  zero_pad<<<5292, 256, 0, stream>>>(qkvP);
  gemm_qkv<<<dim3(9, 200), 512, 0, stream>>>(xbf, wqkvT, qkvP);
  win_attn<<<dim3(12, 36, 8), 256, 0, stream>>>(qkvP, aout);
  gemm_proj<<<dim3(3, 200), 512, 0, stream>>>(aout, wprojT, (float*)d_out, bproj);
}